// Round 1
// baseline (5239.533 us; speedup 1.0000x reference)
//
#include <hip/hip_runtime.h>
#include <hip/hip_bf16.h>

#define B_ 64
#define T_ 256
#define D_ 200
#define H_ 300
#define L_ 8
#define M_ 16384      // T_*B_
#define NG 1800       // 6H
#define NZ 1500       // 5H

typedef __attribute__((ext_vector_type(8))) short bf16x8;
typedef __attribute__((ext_vector_type(4))) float f32x4;

__device__ __forceinline__ unsigned short f2bf(float f) {
  union { float f; unsigned u; } v; v.f = f;
  unsigned r = v.u + 0x7fffu + ((v.u >> 16) & 1u);   // RNE
  return (unsigned short)(r >> 16);
}

__device__ __forceinline__ float sigf(float x) { return 1.f / (1.f + __expf(-x)); }
__device__ __forceinline__ float tanhf_(float x) {
  x = fminf(15.f, fmaxf(-15.f, x));
  float e = __expf(2.f * x);
  return (e - 1.f) / (e + 1.f);
}

// ---- weight conversion: W_ih0 (200x1800) then W_ih_rest (7x300x1800) -> bf16 ----
__global__ void k_convert_w(const float* __restrict__ W0, const float* __restrict__ Wr,
                            unsigned short* __restrict__ Wb) {
  int i = blockIdx.x * blockDim.x + threadIdx.x;
  const int n0 = D_ * NG;            // 360000
  const int n1 = (L_ - 1) * H_ * NG; // 3780000
  if (i < n0) Wb[i] = f2bf(W0[i]);
  else if (i < n0 + n1) Wb[i] = f2bf(Wr[i - n0]);
}

// ---- inputs [B,T,D] fp32 -> time-major xb [T,B,D] bf16 ----
__global__ void k_transpose_in(const float* __restrict__ inp, unsigned short* __restrict__ xb) {
  int i = blockIdx.x * blockDim.x + threadIdx.x;     // over T_*B_*D_
  if (i >= T_ * B_ * D_) return;
  int d = i % D_;
  int r = i / D_;       // t*B_+b
  int b = r % B_;
  int t = r / B_;
  xb[i] = f2bf(inp[((size_t)b * T_ + t) * D_ + d]);
}

// ---- hidden[7] [T,B,H] -> output [B,T,H] ----
__global__ void k_out(const float* __restrict__ hid7, float* __restrict__ outp) {
  int i = blockIdx.x * blockDim.x + threadIdx.x;     // over B_*T_*H_
  if (i >= B_ * T_ * H_) return;
  int j = i % H_;
  int r = i / H_;
  int t = r % T_;
  int b = r / T_;
  outp[i] = hid7[((size_t)t * B_ + b) * H_ + j];
}

// ---- pi GEMM: C[M,1800] fp32 = A[M,K] bf16 * B[K,1800] bf16 ----
__global__ __launch_bounds__(256) void k_gemm(const unsigned short* __restrict__ A,
                                              const unsigned short* __restrict__ Bw,
                                              float* __restrict__ C, int K) {
  __shared__ unsigned short As[64 * 40];
  __shared__ unsigned short Bs[64 * 40];
  int bm = blockIdx.x, bn = blockIdx.y;
  int tid = threadIdx.x;
  int lane = tid & 63, wid = tid >> 6;
  int wm = wid & 1, wn = wid >> 1;
  int l16 = lane & 15, quad = lane >> 4;
  f32x4 acc00 = {0,0,0,0}, acc01 = {0,0,0,0}, acc10 = {0,0,0,0}, acc11 = {0,0,0,0};
  int nk = (K + 31) >> 5;
  for (int kc = 0; kc < nk; kc++) {
    int k0 = kc << 5;
    #pragma unroll
    for (int c0 = 0; c0 < 2; c0++) {
      int c = tid + c0 * 256;
      int m = c >> 3, kq = (c & 7) << 2;
      int kk = k0 + kq;
      uint2 val = make_uint2(0u, 0u);
      if (kk < K) val = *(const uint2*)(A + (size_t)(bm * 64 + m) * K + kk);
      *(uint2*)(&As[m * 40 + kq]) = val;
    }
    #pragma unroll
    for (int c0 = 0; c0 < 2; c0++) {
      int c = tid + c0 * 256;
      int krow = c >> 4, nq = (c & 15) << 2;
      int col = bn * 64 + nq;
      uint2 val = make_uint2(0u, 0u);
      if ((k0 + krow) < K && col < NG)
        val = *(const uint2*)(Bw + (size_t)(k0 + krow) * NG + col);
      const unsigned short* pv = (const unsigned short*)&val;
      Bs[(nq + 0) * 40 + krow] = pv[0];
      Bs[(nq + 1) * 40 + krow] = pv[1];
      Bs[(nq + 2) * 40 + krow] = pv[2];
      Bs[(nq + 3) * 40 + krow] = pv[3];
    }
    __syncthreads();
    bf16x8 a0 = *(const bf16x8*)&As[(wm * 32 + l16) * 40 + quad * 8];
    bf16x8 a1 = *(const bf16x8*)&As[(wm * 32 + 16 + l16) * 40 + quad * 8];
    bf16x8 b0 = *(const bf16x8*)&Bs[(wn * 32 + l16) * 40 + quad * 8];
    bf16x8 b1 = *(const bf16x8*)&Bs[(wn * 32 + 16 + l16) * 40 + quad * 8];
    acc00 = __builtin_amdgcn_mfma_f32_16x16x32_bf16(a0, b0, acc00, 0, 0, 0);
    acc01 = __builtin_amdgcn_mfma_f32_16x16x32_bf16(a0, b1, acc01, 0, 0, 0);
    acc10 = __builtin_amdgcn_mfma_f32_16x16x32_bf16(a1, b0, acc10, 0, 0, 0);
    acc11 = __builtin_amdgcn_mfma_f32_16x16x32_bf16(a1, b1, acc11, 0, 0, 0);
    __syncthreads();
  }
  int rowb = bm * 64 + wm * 32 + quad * 4;
  int colb = bn * 64 + wn * 32 + l16;
  #pragma unroll
  for (int i = 0; i < 4; i++) {
    if (colb < NG) {
      C[(size_t)(rowb + i) * NG + colb] = acc00[i];
      C[(size_t)(rowb + 16 + i) * NG + colb] = acc10[i];
    }
    if (colb + 16 < NG) {
      C[(size_t)(rowb + i) * NG + colb + 16] = acc01[i];
      C[(size_t)(rowb + 16 + i) * NG + colb + 16] = acc11[i];
    }
  }
}

// ---- persistent recurrence: 192 blocks = 16 batch-groups (4 rows) x 12 column-blocks ----
// Dot z[4x125] = h[4x300] @ Whh[300x125] via MFMA (M padded to 16, K to 320,
// N=128 = 8 tiles, one per wave). Whh B-frags preloaded in VGPRs (40/thread).
// h exchange (R5): u64 words = (tag32<<32 | h[2rp]<<16 | h[2rp+1]), i.e. one
// tagged word carries TWO batch rows at one column. 600 words/group (was 1200
// u32), 50 publishes/block (was 100), poll = 1 dwordx2 atomic/thread/iter for
// most threads (was 3 dword). Naturally-aligned u64 global access is
// single-copy atomic -> tag still validates payload with no ordering hop.
// Gate threads: 50, each owns 2 rows x 1 col; c state in registers.
__global__ __launch_bounds__(512, 2) void k_recur(
    const float* __restrict__ pi, const float* __restrict__ Whh,
    const float* __restrict__ bias, const int* __restrict__ lens,
    float* __restrict__ hid, unsigned short* __restrict__ xb,
    unsigned long long* __restrict__ h_words, int rev, int tagbase)
{
  __shared__ __align__(16) unsigned short h_lds[16 * 328]; // bf16 [row][k], rows 4-15 & k>=300 zero
  __shared__ __align__(16) float z_lds[128 * 4];           // [n][r]
  __shared__ float bias_s[128];
  __shared__ int len_s[4];

  const int tid = threadIdx.x;
  const int bid = blockIdx.x;
  const int g = bid & 15;    // batch group
  const int cb = bid >> 4;   // column block 0..11

  const int lane = tid & 63;
  const int wid = tid >> 6;          // 0..7 = N-tile index
  const int l16 = lane & 15;
  const int quad = lane >> 4;

  const int rp = tid / 25;           // gate mapping (tid<50): row-pair 0..1
  const int gj = tid - rp * 25;      // j within 25
  const int j2 = cb * 25 + gj;

  // ---- preload Whh B-fragments: wfrag[c], n = wid*16+l16, k = c*32+quad*8+j ----
  bf16x8 wfrag[10];
  {
    int n = wid * 16 + l16;
    bool vn = n < 125;
    int colw = vn ? ((n / 25) * 300 + cb * 25 + (n % 25)) : 0;
    #pragma unroll
    for (int c = 0; c < 10; c++) {
      bf16x8 f;
      #pragma unroll
      for (int j = 0; j < 8; j++) {
        int k = c * 32 + quad * 8 + j;
        float v = (vn && k < 300) ? Whh[(size_t)k * NZ + colw] : 0.f;
        f[j] = (short)f2bf(v);
      }
      wfrag[c] = f;
    }
  }
  if (tid < 4) len_s[tid] = lens[g * 4 + tid];
  if (tid < 125) bias_s[tid] = bias[(tid / 25) * 300 + cb * 25 + (tid % 25)];
  for (int i = tid; i < 16 * 328; i += 512) h_lds[i] = 0;  // zero pad rows/cols
  __syncthreads();

  int S = len_s[0];
  S = len_s[1] > S ? len_s[1] : S;
  S = len_s[2] > S ? len_s[2] : S;
  S = len_s[3] > S ? len_s[3] : S;

  unsigned long long* hw = h_words + (size_t)g * 1200;   // [parity][600] u64
  const int brbase = g * 4;
  const bool p2 = tid < 88;          // 600 - 512 = 88 extra words
  float cA = 0.f, cB = 0.f;          // cell state, rows 2rp / 2rp+1 (tid<50)

  for (int s = 0; s < S; s++) {
    // gate threads prefetch their 12 pi values (in flight across the poll)
    float pA0 = 0.f, pA1 = 0.f, pA2 = 0.f, pA3 = 0.f, pA4 = 0.f, pA6 = 0.f;
    float pB0 = 0.f, pB1 = 0.f, pB2 = 0.f, pB3 = 0.f, pB4 = 0.f, pB6 = 0.f;
    if (tid < 50) {
      int lrA = len_s[2 * rp], lrB = len_s[2 * rp + 1];
      if (s < lrA) {
        int t = rev ? (lrA - 1 - s) : s;
        const float* pr = pi + ((size_t)t * B_ + (brbase + 2 * rp)) * NG;
        pA0 = pr[0 * 300 + j2]; pA1 = pr[1 * 300 + j2]; pA2 = pr[2 * 300 + j2];
        pA3 = pr[3 * 300 + j2]; pA4 = pr[4 * 300 + j2]; pA6 = pr[NZ + j2];
      }
      if (s < lrB) {
        int t = rev ? (lrB - 1 - s) : s;
        const float* pr = pi + ((size_t)t * B_ + (brbase + 2 * rp + 1)) * NG;
        pB0 = pr[0 * 300 + j2]; pB1 = pr[1 * 300 + j2]; pB2 = pr[2 * 300 + j2];
        pB3 = pr[3 * 300 + j2]; pB4 = pr[4 * 300 + j2]; pB6 = pr[NZ + j2];
      }
    }

    if (s > 0) {
      const unsigned tg = (unsigned)(tagbase + s);          // tag of h_s
      const unsigned long long* buf = hw + (size_t)(s & 1) * 600;
      unsigned long long v0, v1 = 0ull;
      for (;;) {
        v0 = __hip_atomic_load(buf + tid, __ATOMIC_RELAXED, __HIP_MEMORY_SCOPE_AGENT);
        if (p2)
          v1 = __hip_atomic_load(buf + tid + 512, __ATOMIC_RELAXED, __HIP_MEMORY_SCOPE_AGENT);
        bool ok = ((unsigned)(v0 >> 32) == tg);
        if (p2) ok = ok && ((unsigned)(v1 >> 32) == tg);
        if (ok) break;
        __builtin_amdgcn_s_sleep(1);   // backoff: cut fabric spin traffic
      }
      // stash bf16 payloads into LDS A-operand layout (2 rows per word)
      int w = tid, r2 = w / 300, k = w - r2 * 300;
      h_lds[(2 * r2) * 328 + k]     = (unsigned short)(v0 >> 16);
      h_lds[(2 * r2 + 1) * 328 + k] = (unsigned short)v0;
      if (p2) {
        w = tid + 512; r2 = w / 300; k = w - r2 * 300;
        h_lds[(2 * r2) * 328 + k]     = (unsigned short)(v1 >> 16);
        h_lds[(2 * r2 + 1) * 328 + k] = (unsigned short)v1;
      }
    }
    __syncthreads();

    f32x4 acc = {0, 0, 0, 0};
    if (s > 0) {
      f32x4 acc2 = {0, 0, 0, 0};
      const unsigned short* abase = &h_lds[l16 * 328 + quad * 8];
      #pragma unroll
      for (int c = 0; c < 10; c += 2) {
        bf16x8 a0 = *(const bf16x8*)(abase + c * 32);
        bf16x8 a1 = *(const bf16x8*)(abase + c * 32 + 32);
        acc  = __builtin_amdgcn_mfma_f32_16x16x32_bf16(a0, wfrag[c],     acc,  0, 0, 0);
        acc2 = __builtin_amdgcn_mfma_f32_16x16x32_bf16(a1, wfrag[c + 1], acc2, 0, 0, 0);
      }
      acc += acc2;
    }
    // C layout: col=lane&15, row=quad*4+reg -> lanes 0-15 hold rows 0-3 in regs 0-3
    if (quad == 0) {
      int n = wid * 16 + l16;
      *(f32x4*)&z_lds[n * 4] = acc;
    }
    __syncthreads();

    if (tid < 50) {
      const float bb0 = bias_s[gj],      bb1 = bias_s[25 + gj], bb2 = bias_s[50 + gj];
      const float bb3 = bias_s[75 + gj], bb4 = bias_s[100 + gj];
      const float2 z0 = *(const float2*)&z_lds[(gj      ) * 4 + 2 * rp];
      const float2 z1 = *(const float2*)&z_lds[(25 + gj ) * 4 + 2 * rp];
      const float2 z2 = *(const float2*)&z_lds[(50 + gj ) * 4 + 2 * rp];
      const float2 z3 = *(const float2*)&z_lds[(75 + gj ) * 4 + 2 * rp];
      const float2 z4 = *(const float2*)&z_lds[(100 + gj) * 4 + 2 * rp];
      // row A = 2rp
      float iA = sigf(z0.x + pA0 + bb0);
      float fA = sigf(z1.x + pA1 + bb1);
      float gA = tanhf_(z2.x + pA2 + bb2);
      float oA = sigf(z3.x + pA3 + bb3);
      float rA = sigf(z4.x + pA4 + bb4);
      float cnA = iA * gA + fA * cA; cA = cnA;
      float hA = rA * (oA * tanhf_(cnA)) + (1.f - rA) * pA6;
      // row B = 2rp+1
      float iB = sigf(z0.y + pB0 + bb0);
      float fB = sigf(z1.y + pB1 + bb1);
      float gB = tanhf_(z2.y + pB2 + bb2);
      float oB = sigf(z3.y + pB3 + bb3);
      float rB = sigf(z4.y + pB4 + bb4);
      float cnB = iB * gB + fB * cB; cB = cnB;
      float hB = rB * (oB * tanhf_(cnB)) + (1.f - rB) * pB6;

      unsigned short hbA = f2bf(hA), hbB = f2bf(hB);
      unsigned long long word = ((unsigned long long)(unsigned)(tagbase + s + 1) << 32)
                              | ((unsigned)hbA << 16) | (unsigned)hbB;
      __hip_atomic_store(&hw[(size_t)((s + 1) & 1) * 600 + rp * 300 + j2], word,
                         __ATOMIC_RELAXED, __HIP_MEMORY_SCOPE_AGENT);
      int lrA = len_s[2 * rp], lrB = len_s[2 * rp + 1];
      if (s < lrA) {
        int t = rev ? (lrA - 1 - s) : s;
        int br = brbase + 2 * rp;
        hid[((size_t)t * B_ + br) * H_ + j2] = hA;
        xb[((size_t)t * B_ + br) * H_ + j2] = hbA;
      }
      if (s < lrB) {
        int t = rev ? (lrB - 1 - s) : s;
        int br = brbase + 2 * rp + 1;
        hid[((size_t)t * B_ + br) * H_ + j2] = hB;
        xb[((size_t)t * B_ + br) * H_ + j2] = hbB;
      }
    }
    // no trailing barrier needed: next stash can only start after our own gates
    // publish (we poll our own words too); h_lds/z_lds hazards separated by the
    // two barriers above.
  }
}

extern "C" void kernel_launch(void* const* d_in, const int* in_sizes, int n_in,
                              void* d_out, int out_size, void* d_ws, size_t ws_size,
                              hipStream_t stream) {
  const float* inputs = (const float*)d_in[0];
  const int* lengths = (const int*)d_in[1];
  const float* W_ih0 = (const float*)d_in[2];
  const float* W_ih_rest = (const float*)d_in[3];
  const float* W_hh = (const float*)d_in[4];
  const float* b_hh = (const float*)d_in[5];
  float* outp = (float*)d_out;
  float* hidden = outp + (size_t)B_ * T_ * H_;   // [L][T,B,H]

  char* ws = (char*)d_ws;
  float* pi = (float*)ws;                                         // M_*NG fp32 (118MB)
  size_t off = (size_t)M_ * NG * 4;
  unsigned short* xb = (unsigned short*)(ws + off);               // M_*H_ bf16
  off += (size_t)M_ * H_ * 2;
  unsigned short* Wb = (unsigned short*)(ws + off);               // 4,140,000 bf16
  off += 4140000ull * 2;
  unsigned long long* h_words = (unsigned long long*)(ws + off);  // 16 groups * 2 * 600 u64
  off += 16ull * 1200 * 8;

  hipMemsetAsync(d_out, 0, (size_t)out_size * 4, stream);         // zero padding regions
  hipMemsetAsync(h_words, 0, 16ull * 1200 * 8, stream);           // clear tags

  {
    int n = D_ * NG + (L_ - 1) * H_ * NG;
    k_convert_w<<<(n + 255) / 256, 256, 0, stream>>>(W_ih0, W_ih_rest, Wb);
  }
  {
    int n = T_ * B_ * D_;
    k_transpose_in<<<(n + 255) / 256, 256, 0, stream>>>(inputs, xb);
  }
  for (int l = 0; l < L_; l++) {
    const unsigned short* Wihb = (l == 0) ? Wb : (Wb + 360000 + (size_t)(l - 1) * 540000);
    int K = (l == 0) ? D_ : H_;
    k_gemm<<<dim3(M_ / 64, (NG + 63) / 64), 256, 0, stream>>>(xb, Wihb, pi, K);
    float* hid_l = hidden + (size_t)l * T_ * B_ * H_;
    k_recur<<<192, 512, 0, stream>>>(pi, W_hh + (size_t)l * H_ * NZ, b_hh + (size_t)l * NZ,
                                     lengths, hid_l, xb, h_words, l & 1, l * 300);
  }
  k_out<<<((B_ * T_ * H_) + 255) / 256, 256, 0, stream>>>(
      hidden + (size_t)(L_ - 1) * T_ * B_ * H_, outp);
}